// Round 2
// baseline (569.101 us; speedup 1.0000x reference)
//
#include <hip/hip_runtime.h>
#include <hip/hip_bf16.h>
#include <stdint.h>

typedef unsigned short u16;

#define Adim 512
#define Ndim 128
#define Fdim 256
#define BA 2048

#define HS 264      // bf16 row stride: 528 B, 16B-aligned, +8-granule bank rotation
#define XS 264

typedef __attribute__((ext_vector_type(8))) __bf16 bf16x8;
typedef __attribute__((ext_vector_type(4))) float f32x4;

union pack8 { bf16x8 v; u16 u[8]; };
union pack4 { uint2 q; u16 u[4]; };

__device__ __forceinline__ float bf2f(u16 u){
  uint32_t v = ((uint32_t)u) << 16;
  return __builtin_bit_cast(float, v);
}
__device__ __forceinline__ u16 f2bf(float f){
  uint32_t v = __builtin_bit_cast(uint32_t, f);
  v += 0x7fffu + ((v >> 16) & 1u);     // RNE
  return (u16)(v >> 16);
}
// softplus(v) - log(2), stable both tails
__device__ __forceinline__ float ssp_f(float v){
  float m = fmaxf(v, 0.f);
  float e = __expf(-fabsf(v));
  return m + __logf(1.f + e) - 0.69314718f;
}

// ---------------- prep: transpose fp32 256x256 -> bf16 [n][k], x3 ----------------
__global__ __launch_bounds__(256) void prep_kernel(
    const float* __restrict__ s0, u16* __restrict__ d0,
    const float* __restrict__ s1, u16* __restrict__ d1,
    const float* __restrict__ s2, u16* __restrict__ d2)
{
  __shared__ float tile[32][33];
  const float* src = (blockIdx.y == 0) ? s0 : (blockIdx.y == 1 ? s1 : s2);
  u16* dst = (blockIdx.y == 0) ? d0 : (blockIdx.y == 1 ? d1 : d2);
  int bx = (blockIdx.x & 7) * 32, by = (int)(blockIdx.x >> 3) * 32;
  int tx = threadIdx.x & 31, ty = threadIdx.x >> 5;
  #pragma unroll
  for (int r = 0; r < 4; r++)
    tile[ty + r*8][tx] = src[(size_t)(by + ty + r*8)*Fdim + bx + tx];
  __syncthreads();
  #pragma unroll
  for (int r = 0; r < 4; r++)
    dst[(size_t)(bx + ty + r*8)*Fdim + by + tx] = f2bf(tile[tx][ty + r*8]);
}

// ---------------- facts = x @ in2f_w + b  (MFMA, bf16 out) ----------------
__global__ __launch_bounds__(256, 2) void facts_kernel(
    const float* __restrict__ x, const u16* __restrict__ wT,
    const float* __restrict__ bias, u16* __restrict__ facts)
{
  __shared__ __align__(16) u16 Xs[64*HS];
  const int tid = threadIdx.x;
  const int row0 = blockIdx.x * 64;

  #pragma unroll
  for (int i = 0; i < 16; i++){
    int id = i*256 + tid;
    int r = id >> 6, c4 = id & 63;
    float4 v = *(const float4*)(x + (size_t)(row0 + r)*Fdim + c4*4);
    pack4 p;
    p.u[0] = f2bf(v.x); p.u[1] = f2bf(v.y); p.u[2] = f2bf(v.z); p.u[3] = f2bf(v.w);
    *(uint2*)(Xs + r*HS + c4*4) = p.q;
  }
  __syncthreads();

  const int lane = tid & 63, wid = tid >> 6;
  const int wcol = wid * 64;
  const int l16 = lane & 15, quad = lane >> 4;

  f32x4 acc[4][4];
  #pragma unroll
  for (int mt = 0; mt < 4; mt++)
    #pragma unroll
    for (int ct = 0; ct < 4; ct++)
      acc[mt][ct] = (f32x4){0.f,0.f,0.f,0.f};

  const u16* wbase = wT + (size_t)(wcol + l16)*Fdim + quad*8;
  bf16x8 bb[2][4];
  #pragma unroll
  for (int ct = 0; ct < 4; ct++) bb[0][ct] = *(const bf16x8*)(wbase + ct*16*Fdim);

  for (int kk = 0; kk < 8; kk++){
    if (kk < 7){
      #pragma unroll
      for (int ct = 0; ct < 4; ct++)
        bb[(kk+1)&1][ct] = *(const bf16x8*)(wbase + ct*16*Fdim + (kk+1)*32);
    }
    bf16x8 af[4];
    #pragma unroll
    for (int mt = 0; mt < 4; mt++)
      af[mt] = *(const bf16x8*)(Xs + (mt*16 + l16)*HS + kk*32 + quad*8);
    #pragma unroll
    for (int mt = 0; mt < 4; mt++)
      #pragma unroll
      for (int ct = 0; ct < 4; ct++)
        acc[mt][ct] = __builtin_amdgcn_mfma_f32_16x16x32_bf16(af[mt], bb[kk&1][ct], acc[mt][ct], 0, 0, 0);
  }

  #pragma unroll
  for (int ct = 0; ct < 4; ct++){
    int f = wcol + ct*16 + l16;
    float bv = bias[f];
    #pragma unroll
    for (int mt = 0; mt < 4; mt++)
      #pragma unroll
      for (int i = 0; i < 4; i++){
        int m = mt*16 + quad*4 + i;
        facts[(size_t)(row0 + m)*Fdim + f] = f2bf(acc[mt][ct][i] + bv);
      }
  }
}

// ---------------- fused: W=ssp(r*fw1+fb1)@fw2+fb2 ; y=xi*W*xj ; out=ssp(y@f2out+b) ----
__global__ __launch_bounds__(256, 2) void fused_kernel(
    const float* __restrict__ r_ij, const u16* __restrict__ facts,
    const u16* __restrict__ fw2T, const u16* __restrict__ f2outT,
    const float* __restrict__ fw1, const float* __restrict__ fb1,
    const float* __restrict__ fb2, const float* __restrict__ f2out_b,
    const int* __restrict__ neighbors, float* __restrict__ out)
{
  __shared__ __align__(16) u16 Hs[64*HS];   // 33792 B (H, then Y)
  __shared__ __align__(16) u16 XJ[64*XS];   // 33792 B
  __shared__ int   nb_s[64];
  __shared__ float r_s[64];

  const int tid  = threadIdx.x;
  const int pair = blockIdx.x >> 1;          // b*Adim + a
  const int half = blockIdx.x & 1;
  const int rbase = half * 64;
  const int bbase = (pair / Adim) * Adim;    // b*Adim

  if (tid < 64){
    nb_s[tid] = neighbors[(size_t)pair*Ndim + rbase + tid];
    r_s[tid]  = r_ij[(size_t)pair*Ndim + rbase + tid];
  }
  __syncthreads();

  // ---- gather xj rows into regs (global, L2-resident facts) ----
  float4 gx[8];
  #pragma unroll
  for (int i = 0; i < 8; i++){
    int id = i*256 + tid;
    int row = id >> 5, ch = id & 31;
    gx[i] = *(const float4*)(facts + ((size_t)(bbase + nb_s[row]))*Fdim + ch*8);
  }

  // ---- H[row][f] = ssp(r[row]*fw1[f]+fb1[f]), vectorized b128 writes ----
  #pragma unroll
  for (int i = 0; i < 8; i++){
    int id = i*256 + tid;
    int row = id >> 5, g = id & 31;
    float rv = r_s[row];
    float wv[8], cv[8];
    *(float4*)(wv)   = *(const float4*)(fw1 + g*8);
    *(float4*)(wv+4) = *(const float4*)(fw1 + g*8 + 4);
    *(float4*)(cv)   = *(const float4*)(fb1 + g*8);
    *(float4*)(cv+4) = *(const float4*)(fb1 + g*8 + 4);
    pack8 p;
    #pragma unroll
    for (int j = 0; j < 8; j++)
      p.u[j] = f2bf(ssp_f(fmaf(rv, wv[j], cv[j])));
    *(bf16x8*)(Hs + row*HS + g*8) = p.v;
  }

  // ---- spill gathered xj to LDS ----
  #pragma unroll
  for (int i = 0; i < 8; i++){
    int id = i*256 + tid;
    int row = id >> 5, ch = id & 31;
    *(float4*)(XJ + row*XS + ch*8) = gx[i];
  }

  const int lane = tid & 63, wid = tid >> 6;
  const int wcol = wid * 64;
  const int l16  = lane & 15, quad = lane >> 4;

  const u16* w1base = fw2T   + (size_t)(wcol + l16)*Fdim + quad*8;
  const u16* w2base = f2outT + (size_t)(wcol + l16)*Fdim + quad*8;

  f32x4 acc[4][4];
  #pragma unroll
  for (int mt = 0; mt < 4; mt++)
    #pragma unroll
    for (int ct = 0; ct < 4; ct++)
      acc[mt][ct] = (f32x4){0.f,0.f,0.f,0.f};

  // 2-deep B prefetch (global)
  bf16x8 bb[2][4];
  #pragma unroll
  for (int ct = 0; ct < 4; ct++){
    bb[0][ct] = *(const bf16x8*)(w1base + ct*16*Fdim);
    bb[1][ct] = *(const bf16x8*)(w1base + ct*16*Fdim + 32);
  }

  __syncthreads();   // Hs + XJ ready

  // ---- GEMM1: W = H @ fw2 ----
  for (int kk = 0; kk < 8; kk++){
    bf16x8 bu[4];
    #pragma unroll
    for (int ct = 0; ct < 4; ct++) bu[ct] = bb[kk&1][ct];
    if (kk < 6){
      #pragma unroll
      for (int ct = 0; ct < 4; ct++)
        bb[kk&1][ct] = *(const bf16x8*)(w1base + ct*16*Fdim + (kk+2)*32);
    } else {
      #pragma unroll
      for (int ct = 0; ct < 4; ct++)
        bb[kk&1][ct] = *(const bf16x8*)(w2base + ct*16*Fdim + (kk-6)*32);
    }
    bf16x8 af[4];
    #pragma unroll
    for (int mt = 0; mt < 4; mt++)
      af[mt] = *(const bf16x8*)(Hs + (mt*16 + l16)*HS + kk*32 + quad*8);
    #pragma unroll
    for (int mt = 0; mt < 4; mt++)
      #pragma unroll
      for (int ct = 0; ct < 4; ct++)
        acc[mt][ct] = __builtin_amdgcn_mfma_f32_16x16x32_bf16(af[mt], bu[ct], acc[mt][ct], 0, 0, 0);
  }

  // ---- elementwise: Y = xi * (W + fb2) * xj -> Hs (bf16) ----
  __syncthreads();   // all GEMM1 A-frag reads done
  #pragma unroll
  for (int ct = 0; ct < 4; ct++){
    int f = wcol + ct*16 + l16;
    float xif  = bf2f(facts[(size_t)pair*Fdim + f]);
    float fb2v = fb2[f];
    #pragma unroll
    for (int mt = 0; mt < 4; mt++){
      #pragma unroll
      for (int i = 0; i < 4; i++){
        int m = mt*16 + quad*4 + i;          // C/D layout: col=lane&15, row=quad*4+i
        float wv = acc[mt][ct][i] + fb2v;
        float y  = xif * wv * bf2f(XJ[m*XS + f]);
        Hs[m*HS + f] = f2bf(y);
        acc[mt][ct][i] = 0.f;
      }
    }
  }
  __syncthreads();   // Y ready

  // ---- GEMM2: Z = Y @ f2out_w ----
  for (int kk = 0; kk < 8; kk++){
    bf16x8 bu[4];
    #pragma unroll
    for (int ct = 0; ct < 4; ct++) bu[ct] = bb[kk&1][ct];
    if (kk < 6){
      #pragma unroll
      for (int ct = 0; ct < 4; ct++)
        bb[kk&1][ct] = *(const bf16x8*)(w2base + ct*16*Fdim + (kk+2)*32);
    }
    bf16x8 af[4];
    #pragma unroll
    for (int mt = 0; mt < 4; mt++)
      af[mt] = *(const bf16x8*)(Hs + (mt*16 + l16)*HS + kk*32 + quad*8);
    #pragma unroll
    for (int mt = 0; mt < 4; mt++)
      #pragma unroll
      for (int ct = 0; ct < 4; ct++)
        acc[mt][ct] = __builtin_amdgcn_mfma_f32_16x16x32_bf16(af[mt], bu[ct], acc[mt][ct], 0, 0, 0);
  }

  // ---- epilogue: out = ssp(Z + f2out_b), nontemporal stores ----
  size_t obase = ((size_t)pair * Ndim + rbase) * Fdim;
  #pragma unroll
  for (int ct = 0; ct < 4; ct++){
    int f = wcol + ct*16 + l16;
    float obv = f2out_b[f];
    #pragma unroll
    for (int mt = 0; mt < 4; mt++){
      #pragma unroll
      for (int i = 0; i < 4; i++){
        int m = mt*16 + quad*4 + i;
        __builtin_nontemporal_store(ssp_f(acc[mt][ct][i] + obv),
                                    out + obase + (size_t)m*Fdim + f);
      }
    }
  }
}

extern "C" void kernel_launch(void* const* d_in, const int* in_sizes, int n_in,
                              void* d_out, int out_size, void* d_ws, size_t ws_size,
                              hipStream_t stream)
{
  const float* x        = (const float*)d_in[0];
  const float* r_ij     = (const float*)d_in[1];
  // d_in[2] pairwise_mask: unused by the reference (all-ones)
  const float* in2f_w   = (const float*)d_in[3];
  const float* in2f_b   = (const float*)d_in[4];
  const float* f2out_w  = (const float*)d_in[5];
  const float* f2out_b  = (const float*)d_in[6];
  const float* fw1      = (const float*)d_in[7];
  const float* fb1      = (const float*)d_in[8];
  const float* fw2      = (const float*)d_in[9];
  const float* fb2      = (const float*)d_in[10];
  const int*   neighbors= (const int*)d_in[11];
  float* out = (float*)d_out;

  u16* facts  = (u16*)d_ws;                                        // 1 MiB
  u16* in2fT  = (u16*)((char*)d_ws + (1u<<20));                    // 128 KiB
  u16* fw2T   = (u16*)((char*)d_ws + (1u<<20) + 1*(1u<<17));       // 128 KiB
  u16* f2outT = (u16*)((char*)d_ws + (1u<<20) + 2*(1u<<17));       // 128 KiB

  prep_kernel<<<dim3(64, 3), 256, 0, stream>>>(in2f_w, in2fT, fw2, fw2T, f2out_w, f2outT);
  facts_kernel<<<32, 256, 0, stream>>>(x, in2fT, in2f_b, facts);
  fused_kernel<<<2*BA, 256, 0, stream>>>(r_ij, facts, fw2T, f2outT,
                                         fw1, fb1, fb2, f2out_b, neighbors, out);
}

// Round 3
// 436.373 us; speedup vs baseline: 1.3042x; 1.3042x over previous
//
#include <hip/hip_runtime.h>
#include <hip/hip_bf16.h>
#include <stdint.h>

typedef unsigned short u16;

#define Adim 512
#define Ndim 128
#define Fdim 256
#define BA 2048

#define HS 264      // bf16 row stride: 528 B, 16B-aligned, 4-dword bank rotation per row
#define XS 264

#define GRID 256
#define ITEMS 16    // 4096 half-pair items / 256 blocks

typedef __attribute__((ext_vector_type(8))) __bf16 bf16x8;
typedef __attribute__((ext_vector_type(4))) float f32x4;

union pack8 { bf16x8 v; u16 u[8]; };
union pack4 { uint2 q; u16 u[4]; };

__device__ __forceinline__ float bf2f(u16 u){
  uint32_t v = ((uint32_t)u) << 16;
  return __builtin_bit_cast(float, v);
}
__device__ __forceinline__ u16 f2bf(float f){
  uint32_t v = __builtin_bit_cast(uint32_t, f);
  v += 0x7fffu + ((v >> 16) & 1u);     // RNE
  return (u16)(v >> 16);
}
// softplus(v) - log(2), stable both tails
__device__ __forceinline__ float ssp_f(float v){
  float m = fmaxf(v, 0.f);
  float e = __expf(-fabsf(v));
  return m + __logf(1.f + e) - 0.69314718f;
}

// ---------------- prep: transpose fp32 256x256 -> bf16 [n][k], x3 ----------------
__global__ __launch_bounds__(256) void prep_kernel(
    const float* __restrict__ s0, u16* __restrict__ d0,
    const float* __restrict__ s1, u16* __restrict__ d1,
    const float* __restrict__ s2, u16* __restrict__ d2)
{
  __shared__ float tile[32][33];
  const float* src = (blockIdx.y == 0) ? s0 : (blockIdx.y == 1 ? s1 : s2);
  u16* dst = (blockIdx.y == 0) ? d0 : (blockIdx.y == 1 ? d1 : d2);
  int bx = (blockIdx.x & 7) * 32, by = (int)(blockIdx.x >> 3) * 32;
  int tx = threadIdx.x & 31, ty = threadIdx.x >> 5;
  #pragma unroll
  for (int r = 0; r < 4; r++)
    tile[ty + r*8][tx] = src[(size_t)(by + ty + r*8)*Fdim + bx + tx];
  __syncthreads();
  #pragma unroll
  for (int r = 0; r < 4; r++)
    dst[(size_t)(bx + ty + r*8)*Fdim + by + tx] = f2bf(tile[tx][ty + r*8]);
}

// ---------------- facts = x @ in2f_w + b  (MFMA, bf16 out) ----------------
__global__ __launch_bounds__(256, 2) void facts_kernel(
    const float* __restrict__ x, const u16* __restrict__ wT,
    const float* __restrict__ bias, u16* __restrict__ facts)
{
  __shared__ __align__(16) u16 Xs[64*HS];
  const int tid = threadIdx.x;
  const int row0 = blockIdx.x * 64;

  #pragma unroll
  for (int i = 0; i < 16; i++){
    int id = i*256 + tid;
    int r = id >> 6, c4 = id & 63;
    float4 v = *(const float4*)(x + (size_t)(row0 + r)*Fdim + c4*4);
    pack4 p;
    p.u[0] = f2bf(v.x); p.u[1] = f2bf(v.y); p.u[2] = f2bf(v.z); p.u[3] = f2bf(v.w);
    *(uint2*)(Xs + r*HS + c4*4) = p.q;
  }
  __syncthreads();

  const int lane = tid & 63, wid = tid >> 6;
  const int wcol = wid * 64;
  const int l16 = lane & 15, quad = lane >> 4;

  f32x4 acc[4][4];
  #pragma unroll
  for (int mt = 0; mt < 4; mt++)
    #pragma unroll
    for (int ct = 0; ct < 4; ct++)
      acc[mt][ct] = (f32x4){0.f,0.f,0.f,0.f};

  const u16* wbase = wT + (size_t)(wcol + l16)*Fdim + quad*8;
  bf16x8 bb[2][4];
  #pragma unroll
  for (int ct = 0; ct < 4; ct++) bb[0][ct] = *(const bf16x8*)(wbase + ct*16*Fdim);

  for (int kk = 0; kk < 8; kk++){
    if (kk < 7){
      #pragma unroll
      for (int ct = 0; ct < 4; ct++)
        bb[(kk+1)&1][ct] = *(const bf16x8*)(wbase + ct*16*Fdim + (kk+1)*32);
    }
    bf16x8 af[4];
    #pragma unroll
    for (int mt = 0; mt < 4; mt++)
      af[mt] = *(const bf16x8*)(Xs + (mt*16 + l16)*HS + kk*32 + quad*8);
    #pragma unroll
    for (int mt = 0; mt < 4; mt++)
      #pragma unroll
      for (int ct = 0; ct < 4; ct++)
        acc[mt][ct] = __builtin_amdgcn_mfma_f32_16x16x32_bf16(af[mt], bb[kk&1][ct], acc[mt][ct], 0, 0, 0);
  }

  #pragma unroll
  for (int ct = 0; ct < 4; ct++){
    int f = wcol + ct*16 + l16;
    float bv = bias[f];
    #pragma unroll
    for (int mt = 0; mt < 4; mt++)
      #pragma unroll
      for (int i = 0; i < 4; i++){
        int m = mt*16 + quad*4 + i;
        facts[(size_t)(row0 + m)*Fdim + f] = f2bf(acc[mt][ct][i] + bv);
      }
  }
}

// ---- fused, persistent: W=ssp(r*fw1+fb1)@fw2+fb2 ; y=xi*W*xj ; out=ssp(y@f2out+b) ----
__global__ __launch_bounds__(512, 2) void fused_kernel(
    const float* __restrict__ r_ij, const u16* __restrict__ facts,
    const u16* __restrict__ fw2T, const u16* __restrict__ f2outT,
    const float* __restrict__ fw1, const float* __restrict__ fb1,
    const float* __restrict__ fb2, const float* __restrict__ f2out_b,
    const int* __restrict__ neighbors, float* __restrict__ out)
{
  __shared__ __align__(16) u16 Hs[64*HS];   // 33792 B (H, then Y)
  __shared__ __align__(16) u16 XJ[64*XS];   // 33792 B
  __shared__ int   nb_s[64];
  __shared__ float r_s[64];

  const int tid  = threadIdx.x;
  const int lane = tid & 63, wid = tid >> 6;
  const int l16  = lane & 15, quad = lane >> 4;
  const int wcol = wid * 32;                 // 8 waves x 32-col n-slices
  const int g    = tid & 31;                 // gather/H-gen column group (invariant)
  const int rsub = tid >> 5;                 // row sub-index (invariant)

  // ---- per-thread kernel-lifetime register caches ----
  float fw1v[8], fb1v[8];
  *(float4*)(fw1v)   = *(const float4*)(fw1 + g*8);
  *(float4*)(fw1v+4) = *(const float4*)(fw1 + g*8 + 4);
  *(float4*)(fb1v)   = *(const float4*)(fb1 + g*8);
  *(float4*)(fb1v+4) = *(const float4*)(fb1 + g*8 + 4);
  float fb2v[2], obv[2];
  #pragma unroll
  for (int ct = 0; ct < 2; ct++){
    int f = wcol + ct*16 + l16;
    fb2v[ct] = fb2[f];
    obv[ct]  = f2out_b[f];
  }

  const u16* w1base = fw2T   + (size_t)(wcol + l16)*Fdim + quad*8;
  const u16* w2base = f2outT + (size_t)(wcol + l16)*Fdim + quad*8;

  f32x4 acc[4][2];
  #pragma unroll
  for (int mt = 0; mt < 4; mt++)
    #pragma unroll
    for (int ct = 0; ct < 2; ct++)
      acc[mt][ct] = (f32x4){0.f,0.f,0.f,0.f};

  bf16x8 bw[8][2];

  for (int l = 0; l < ITEMS; l++){
    const int item = l*GRID + blockIdx.x;
    const int pair = item >> 1;
    const int half = item & 1;
    const int bbase = (pair >> 9) << 9;      // (pair / Adim) * Adim

    if (tid < 64){
      nb_s[tid] = neighbors[(size_t)pair*Ndim + half*64 + tid];
      r_s[tid]  = r_ij[(size_t)pair*Ndim + half*64 + tid];
    }
    __syncthreads();   // B1: nb/r visible; prev item's GEMM2 reads of Hs done

    // GEMM1 weights -> regs (latency hides behind gather + H-gen VALU)
    #pragma unroll
    for (int kk = 0; kk < 8; kk++)
      #pragma unroll
      for (int ct = 0; ct < 2; ct++)
        bw[kk][ct] = *(const bf16x8*)(w1base + ct*16*Fdim + kk*32);

    // gather xj rows (L2-resident facts) into regs
    float4 gx[4];
    #pragma unroll
    for (int i = 0; i < 4; i++){
      int row = i*16 + rsub;
      gx[i] = *(const float4*)(facts + ((size_t)(bbase + nb_s[row]))*Fdim + g*8);
    }

    // H[row][g*8..+7] = ssp(r*fw1+fb1), b128 LDS writes
    #pragma unroll
    for (int i = 0; i < 4; i++){
      int row = i*16 + rsub;
      float rv = r_s[row];
      pack8 p;
      #pragma unroll
      for (int j = 0; j < 8; j++)
        p.u[j] = f2bf(ssp_f(fmaf(rv, fw1v[j], fb1v[j])));
      *(bf16x8*)(Hs + row*HS + g*8) = p.v;
    }

    // spill gathered xj to LDS
    #pragma unroll
    for (int i = 0; i < 4; i++){
      int row = i*16 + rsub;
      *(float4*)(XJ + row*XS + g*8) = gx[i];
    }
    __syncthreads();   // B2: Hs + XJ ready

    // ---- GEMM1: W = H @ fw2 (B from regs, zero mem-waits in loop) ----
    #pragma unroll
    for (int kk = 0; kk < 8; kk++){
      bf16x8 af[4];
      #pragma unroll
      for (int mt = 0; mt < 4; mt++)
        af[mt] = *(const bf16x8*)(Hs + (mt*16 + l16)*HS + kk*32 + quad*8);
      #pragma unroll
      for (int mt = 0; mt < 4; mt++)
        #pragma unroll
        for (int ct = 0; ct < 2; ct++)
          acc[mt][ct] = __builtin_amdgcn_mfma_f32_16x16x32_bf16(af[mt], bw[kk][ct], acc[mt][ct], 0, 0, 0);
    }
    __syncthreads();   // B3: all GEMM1 A-reads done before Y overwrites Hs

    // GEMM2 weights -> regs (latency hides behind elementwise VALU)
    #pragma unroll
    for (int kk = 0; kk < 8; kk++)
      #pragma unroll
      for (int ct = 0; ct < 2; ct++)
        bw[kk][ct] = *(const bf16x8*)(w2base + ct*16*Fdim + kk*32);

    // ---- elementwise: Y = xi * (W + fb2) * xj -> Hs (bf16) ----
    #pragma unroll
    for (int ct = 0; ct < 2; ct++){
      int f = wcol + ct*16 + l16;
      float xif = bf2f(facts[(size_t)pair*Fdim + f]);
      #pragma unroll
      for (int mt = 0; mt < 4; mt++){
        #pragma unroll
        for (int i = 0; i < 4; i++){
          int m = mt*16 + quad*4 + i;       // C/D layout: col=lane&15, row=quad*4+i
          float wv = acc[mt][ct][i] + fb2v[ct];
          float y  = xif * wv * bf2f(XJ[m*XS + f]);
          Hs[m*HS + f] = f2bf(y);
          acc[mt][ct][i] = 0.f;
        }
      }
    }
    __syncthreads();   // B4: Y ready

    // ---- GEMM2: Z = Y @ f2out_w ----
    #pragma unroll
    for (int kk = 0; kk < 8; kk++){
      bf16x8 af[4];
      #pragma unroll
      for (int mt = 0; mt < 4; mt++)
        af[mt] = *(const bf16x8*)(Hs + (mt*16 + l16)*HS + kk*32 + quad*8);
      #pragma unroll
      for (int mt = 0; mt < 4; mt++)
        #pragma unroll
        for (int ct = 0; ct < 2; ct++)
          acc[mt][ct] = __builtin_amdgcn_mfma_f32_16x16x32_bf16(af[mt], bw[kk][ct], acc[mt][ct], 0, 0, 0);
    }

    // ---- epilogue: out = ssp(Z + f2out_b), nontemporal; re-zero acc ----
    size_t obase = ((size_t)pair * Ndim + half*64) * Fdim;
    #pragma unroll
    for (int ct = 0; ct < 2; ct++){
      int f = wcol + ct*16 + l16;
      #pragma unroll
      for (int mt = 0; mt < 4; mt++){
        #pragma unroll
        for (int i = 0; i < 4; i++){
          int m = mt*16 + quad*4 + i;
          __builtin_nontemporal_store(ssp_f(acc[mt][ct][i] + obv[ct]),
                                      out + obase + (size_t)m*Fdim + f);
          acc[mt][ct][i] = 0.f;
        }
      }
    }
  }
}

extern "C" void kernel_launch(void* const* d_in, const int* in_sizes, int n_in,
                              void* d_out, int out_size, void* d_ws, size_t ws_size,
                              hipStream_t stream)
{
  const float* x        = (const float*)d_in[0];
  const float* r_ij     = (const float*)d_in[1];
  // d_in[2] pairwise_mask: unused by the reference (all-ones)
  const float* in2f_w   = (const float*)d_in[3];
  const float* in2f_b   = (const float*)d_in[4];
  const float* f2out_w  = (const float*)d_in[5];
  const float* f2out_b  = (const float*)d_in[6];
  const float* fw1      = (const float*)d_in[7];
  const float* fb1      = (const float*)d_in[8];
  const float* fw2      = (const float*)d_in[9];
  const float* fb2      = (const float*)d_in[10];
  const int*   neighbors= (const int*)d_in[11];
  float* out = (float*)d_out;

  u16* facts  = (u16*)d_ws;                                        // 1 MiB
  u16* in2fT  = (u16*)((char*)d_ws + (1u<<20));                    // 128 KiB
  u16* fw2T   = (u16*)((char*)d_ws + (1u<<20) + 1*(1u<<17));       // 128 KiB
  u16* f2outT = (u16*)((char*)d_ws + (1u<<20) + 2*(1u<<17));       // 128 KiB

  prep_kernel<<<dim3(64, 3), 256, 0, stream>>>(in2f_w, in2fT, fw2, fw2T, f2out_w, f2outT);
  facts_kernel<<<32, 256, 0, stream>>>(x, in2fT, in2f_b, facts);
  fused_kernel<<<GRID, 512, 0, stream>>>(r_ij, facts, fw2T, f2outT,
                                         fw1, fb1, fb2, f2out_b, neighbors, out);
}